// Round 1
// baseline (24500.462 us; speedup 1.0000x reference)
//
#include <hip/hip_runtime.h>
#include <cstdint>

typedef unsigned long long u64;

#define B_TOTAL 16384
#define K_DIM   1025
#define O_DIM   1025
#define NWORDS  17      // ceil(1025/64); 17*64 = 1088 bits, 63 pad bits (set to 1 on both sides)

// -------- pack binarized weights into bit-rows: bit=1 <=> w >= 0; pad bits (k>=1025) = 1 --------
__global__ void pack_w_kernel(const float* __restrict__ w, int O, u64* __restrict__ out) {
  int idx = blockIdx.x * blockDim.x + threadIdx.x;
  int o = idx / NWORDS, wd = idx % NWORDS;
  if (o >= O) return;
  u64 word = 0;
  int kbase = wd * 64;
  for (int j = 0; j < 64; ++j) {
    int k = kbase + j;
    u64 bit = (k < K_DIM) ? (u64)(w[(size_t)o * K_DIM + k] >= 0.0f) : 1ull;
    word |= bit << j;
  }
  out[idx] = word;
}

// -------- layer 1: f32 GEMM lin = x @ sign(W0)^T, STRICTLY k-sequential per output --------
// (single f32 accumulator per element, k ascending => bitwise-matches BLAS sgemm accumulation)
#define BM 128
#define BN 128
#define BK 32
#define KP 36           // padded LDS row (bank-conflict mitigation)
#define KPAD 1056       // 33 tiles of 32; pad terms are exact +0.0

__global__ __launch_bounds__(512) void l1_kernel(const float* __restrict__ x,
                                                 const float* __restrict__ w0,
                                                 u64* __restrict__ h1b) {
  __shared__ float xs[BM][KP];
  __shared__ float ss[BN][KP];
  __shared__ unsigned char bytes[BM][16];

  const int bt = blockIdx.x, ot = blockIdx.y;
  const int b0 = bt * BM, o0 = ot * BN;
  const int t  = threadIdx.x;
  const int tx = t & 15;      // o direction (8 outputs each)
  const int ty = t >> 4;      // b direction (4 outputs each), 0..31

  float acc[4][8];
#pragma unroll
  for (int i = 0; i < 4; ++i)
#pragma unroll
    for (int j = 0; j < 8; ++j) acc[i][j] = 0.0f;

  for (int kt = 0; kt < KPAD; kt += BK) {
    const bool full = (kt + BK) <= K_DIM;
#pragma unroll
    for (int s = 0; s < 2; ++s) {
      int slot = t + s * 512;              // 1024 float4-slots per array
      int r = slot >> 3, c4 = (slot & 7) * 4;
      { // x tile
        size_t g = (size_t)(b0 + r) * K_DIM + kt + c4;
        float4 v;
        if (full) { v.x = x[g]; v.y = x[g+1]; v.z = x[g+2]; v.w = x[g+3]; }
        else {
          int k = kt + c4;
          v.x = (k   < K_DIM) ? x[g]   : 0.0f;
          v.y = (k+1 < K_DIM) ? x[g+1] : 0.0f;
          v.z = (k+2 < K_DIM) ? x[g+2] : 0.0f;
          v.w = (k+3 < K_DIM) ? x[g+3] : 0.0f;
        }
        *reinterpret_cast<float4*>(&xs[r][c4]) = v;
      }
      { // sign(W0) tile
        int orow = o0 + r; if (orow >= O_DIM) orow = O_DIM - 1;   // clamp address; value unused
        size_t g = (size_t)orow * K_DIM + kt + c4;
        float4 v;
        if (full) { v.x = w0[g]; v.y = w0[g+1]; v.z = w0[g+2]; v.w = w0[g+3]; }
        else {
          int k = kt + c4;
          v.x = (k   < K_DIM) ? w0[g]   : 1.0f;
          v.y = (k+1 < K_DIM) ? w0[g+1] : 1.0f;
          v.z = (k+2 < K_DIM) ? w0[g+2] : 1.0f;
          v.w = (k+3 < K_DIM) ? w0[g+3] : 1.0f;
        }
        float4 b;
        b.x = (v.x >= 0.0f) ? 1.0f : -1.0f;
        b.y = (v.y >= 0.0f) ? 1.0f : -1.0f;
        b.z = (v.z >= 0.0f) ? 1.0f : -1.0f;
        b.w = (v.w >= 0.0f) ? 1.0f : -1.0f;
        *reinterpret_cast<float4*>(&ss[r][c4]) = b;
      }
    }
    __syncthreads();

#pragma unroll
    for (int kk = 0; kk < BK; kk += 4) {
      float4 xv[4], sv[8];
#pragma unroll
      for (int i2 = 0; i2 < 4; ++i2) {          // rotated read order: bank-conflict-free
        int i = (i2 + ty) & 3;
        xv[i] = *reinterpret_cast<const float4*>(&xs[ty * 4 + i][kk]);
      }
#pragma unroll
      for (int j2 = 0; j2 < 8; ++j2) {
        int j = (j2 + tx) & 7;
        sv[j] = *reinterpret_cast<const float4*>(&ss[tx * 8 + j][kk]);
      }
#pragma unroll
      for (int i = 0; i < 4; ++i)
#pragma unroll
        for (int j = 0; j < 8; ++j) {
          // k strictly ascending, single accumulator => sequential f32 rounding
          acc[i][j] += xv[i].x * sv[j].x;
          acc[i][j] += xv[i].y * sv[j].y;
          acc[i][j] += xv[i].z * sv[j].z;
          acc[i][j] += xv[i].w * sv[j].w;
        }
    }
    __syncthreads();
  }

  // epilogue: binarize to bits, pack 64-bit words per (b, o-word)
#pragma unroll
  for (int i = 0; i < 4; ++i) {
    unsigned int by = 0;
#pragma unroll
    for (int j = 0; j < 8; ++j)
      by |= (acc[i][j] >= 0.0f ? 1u : 0u) << j;
    bytes[ty * 4 + i][tx] = (unsigned char)by;
  }
  __syncthreads();
  if (t < 256) {
    int b = t >> 1, w = t & 1;
    u64 word = 0;
#pragma unroll
    for (int m = 0; m < 8; ++m)
      word |= (u64)bytes[b][w * 8 + m] << (8 * m);
    int rem = O_DIM - (o0 + w * 64);             // valid bits in this word
    if (rem <= 0) word = ~0ull;
    else if (rem < 64) word |= (~0ull << rem);   // pad bits = 1
    int widx = ot * 2 + w;
    if (widx < NWORDS)
      h1b[(size_t)(b0 + b) * NWORDS + widx] = word;
  }
}

// -------- layer 2: binary-binary via XOR+popcount; exact integers, emits packed h2 --------
__global__ __launch_bounds__(256) void l2_kernel(const u64* __restrict__ h1b,
                                                 const u64* __restrict__ w1b,
                                                 u64* __restrict__ h2b) {
  __shared__ u64 hs[64][NWORDS];
  const int bt = blockIdx.x;
  const int t = threadIdx.x;
  for (int i = t; i < 64 * NWORDS; i += 256)
    hs[i / NWORDS][i % NWORDS] = h1b[(size_t)(bt * 64 + i / NWORDS) * NWORDS + i % NWORDS];
  __syncthreads();

  const int w = t >> 6, l = t & 63;
  for (int oc = w; oc < NWORDS; oc += 4) {
    int o = oc * 64 + l;
    bool valid = (o < O_DIM);
    int orow = valid ? o : (O_DIM - 1);
    u64 wb[NWORDS];
#pragma unroll
    for (int j = 0; j < NWORDS; ++j) wb[j] = w1b[(size_t)orow * NWORDS + j];
    for (int b = 0; b < 64; ++b) {
      int p = 0;
#pragma unroll
      for (int j = 0; j < NWORDS; ++j) p += __popcll(hs[b][j] ^ wb[j]);
      int lin = K_DIM - 2 * p;                   // 1088 - 2p - 63 pad-matches = 1025 - 2p, exact, odd
      bool bit = valid ? (lin >= 0) : true;      // pad bits = 1
      u64 word = __ballot(bit);
      if (l == 0) h2b[(size_t)(bt * 64 + b) * NWORDS + oc] = word;
    }
  }
}

// -------- layer 3: single output neuron; map sign -> {0,1} --------
__global__ void l3_kernel(const u64* __restrict__ h2b, const u64* __restrict__ w2b,
                          float* __restrict__ out) {
  int b = blockIdx.x * blockDim.x + threadIdx.x;
  if (b >= B_TOTAL) return;
  int p = 0;
#pragma unroll
  for (int j = 0; j < NWORDS; ++j) p += __popcll(h2b[(size_t)b * NWORDS + j] ^ w2b[j]);
  out[b] = ((K_DIM - 2 * p) >= 0) ? 1.0f : 0.0f;
}

extern "C" void kernel_launch(void* const* d_in, const int* in_sizes, int n_in,
                              void* d_out, int out_size, void* d_ws, size_t ws_size,
                              hipStream_t stream) {
  const float* x  = (const float*)d_in[0];
  const float* W0 = (const float*)d_in[1];
  const float* W1 = (const float*)d_in[2];
  const float* W2 = (const float*)d_in[3];
  float* out = (float*)d_out;

  char* ws = (char*)d_ws;
  u64* w1b = (u64*)(ws);               // 1025*17*8 = 139400 B
  u64* w2b = (u64*)(ws + 139776);      // 136 B
  u64* h1b = (u64*)(ws + 140288);      // 16384*17*8 = 2228224 B
  u64* h2b = (u64*)(ws + 2368512);     // 2228224 B  (total ~4.6 MB)

  pack_w_kernel<<<(O_DIM * NWORDS + 255) / 256, 256, 0, stream>>>(W1, O_DIM, w1b);
  pack_w_kernel<<<1, 64, 0, stream>>>(W2, 1, w2b);
  l1_kernel<<<dim3(B_TOTAL / BM, (O_DIM + BN - 1) / BN), 512, 0, stream>>>(x, W0, h1b);
  l2_kernel<<<B_TOTAL / 64, 256, 0, stream>>>(h1b, w1b, h2b);
  l3_kernel<<<B_TOTAL / 256, 256, 0, stream>>>(h2b, w2b, out);
}

// Round 2
// 1074.357 us; speedup vs baseline: 22.8048x; 22.8048x over previous
//
#include <hip/hip_runtime.h>
#include <cstdint>

typedef unsigned long long u64;

#define B_TOTAL 16384
#define K_DIM   1025
#define O_DIM   1025
#define NWORDS  17      // ceil(1025/64); 17*64 = 1088 bits, 63 pad bits (set to 1 on both sides)

// -------- pack binarized weights into bit-rows: bit=1 <=> w >= 0; pad bits (k>=1025) = 1 --------
__global__ void pack_w_kernel(const float* __restrict__ w, int O, u64* __restrict__ out) {
  int idx = blockIdx.x * blockDim.x + threadIdx.x;
  int o = idx / NWORDS, wd = idx % NWORDS;
  if (o >= O) return;
  u64 word = 0;
  int kbase = wd * 64;
  for (int j = 0; j < 64; ++j) {
    int k = kbase + j;
    u64 bit = (k < K_DIM) ? (u64)(w[(size_t)o * K_DIM + k] >= 0.0f) : 1ull;
    word |= bit << j;
  }
  out[idx] = word;
}

// -------- layer 1: f32 GEMM lin = x @ sign(W0)^T, STRICTLY k-sequential per output --------
// Single f32 accumulator per element, k ascending => bitwise-matches BLAS sgemm (proven R1).
// Thread (tx,ty) computes b = b0 + i*32 + ty (i<4), o = o0 + j*16 + tx (j<8).
// Strided mapping keeps all fragment indices compile-time (no scratch, rule #20) and
// makes sv reads 2-way-aliased max (free), xv reads broadcast (conflict-free).
#define BM 128
#define BN 128
#define BK 32
#define KP 36           // padded LDS row: 36 words, keeps float4 alignment
#define KPAD 1056       // 33 tiles of 32; pad terms are exact +0.0

__global__ __launch_bounds__(512) void l1_kernel(const float* __restrict__ x,
                                                 const float* __restrict__ w0,
                                                 u64* __restrict__ h1b) {
  __shared__ float xs[BM][KP];
  __shared__ float ss[BN][KP];
  __shared__ unsigned char bits[BM][BN];   // 16 KB, binarized outputs for repack

  const int bt = blockIdx.x, ot = blockIdx.y;
  const int b0 = bt * BM, o0 = ot * BN;
  const int t  = threadIdx.x;
  const int tx = t & 15;      // o direction
  const int ty = t >> 4;      // b direction, 0..31

  float acc[4][8];
#pragma unroll
  for (int i = 0; i < 4; ++i)
#pragma unroll
    for (int j = 0; j < 8; ++j) acc[i][j] = 0.0f;

  for (int kt = 0; kt < KPAD; kt += BK) {
    const bool full = (kt + BK) <= K_DIM;
#pragma unroll
    for (int s = 0; s < 2; ++s) {
      int slot = t + s * 512;              // 1024 float4-slots per array
      int r = slot >> 3, c4 = (slot & 7) * 4;
      { // x tile
        size_t g = (size_t)(b0 + r) * K_DIM + kt + c4;
        float4 v;
        if (full) { v.x = x[g]; v.y = x[g+1]; v.z = x[g+2]; v.w = x[g+3]; }
        else {
          int k = kt + c4;
          v.x = (k   < K_DIM) ? x[g]   : 0.0f;
          v.y = (k+1 < K_DIM) ? x[g+1] : 0.0f;
          v.z = (k+2 < K_DIM) ? x[g+2] : 0.0f;
          v.w = (k+3 < K_DIM) ? x[g+3] : 0.0f;
        }
        *reinterpret_cast<float4*>(&xs[r][c4]) = v;
      }
      { // sign(W0) tile
        int orow = o0 + r; if (orow >= O_DIM) orow = O_DIM - 1;   // clamp address; value unused
        size_t g = (size_t)orow * K_DIM + kt + c4;
        float4 v;
        if (full) { v.x = w0[g]; v.y = w0[g+1]; v.z = w0[g+2]; v.w = w0[g+3]; }
        else {
          int k = kt + c4;
          v.x = (k   < K_DIM) ? w0[g]   : 1.0f;
          v.y = (k+1 < K_DIM) ? w0[g+1] : 1.0f;
          v.z = (k+2 < K_DIM) ? w0[g+2] : 1.0f;
          v.w = (k+3 < K_DIM) ? w0[g+3] : 1.0f;
        }
        float4 b;
        b.x = (v.x >= 0.0f) ? 1.0f : -1.0f;
        b.y = (v.y >= 0.0f) ? 1.0f : -1.0f;
        b.z = (v.z >= 0.0f) ? 1.0f : -1.0f;
        b.w = (v.w >= 0.0f) ? 1.0f : -1.0f;
        *reinterpret_cast<float4*>(&ss[r][c4]) = b;
      }
    }
    __syncthreads();

#pragma unroll
    for (int kk = 0; kk < BK; kk += 4) {
      float4 xv[4], sv[8];
#pragma unroll
      for (int i = 0; i < 4; ++i)          // compile-time indices after unroll -> registers
        xv[i] = *reinterpret_cast<const float4*>(&xs[i * 32 + ty][kk]);
#pragma unroll
      for (int j = 0; j < 8; ++j)
        sv[j] = *reinterpret_cast<const float4*>(&ss[j * 16 + tx][kk]);
#pragma unroll
      for (int i = 0; i < 4; ++i)
#pragma unroll
        for (int j = 0; j < 8; ++j) {
          // k strictly ascending, single accumulator => sequential f32 rounding
          acc[i][j] += xv[i].x * sv[j].x;
          acc[i][j] += xv[i].y * sv[j].y;
          acc[i][j] += xv[i].z * sv[j].z;
          acc[i][j] += xv[i].w * sv[j].w;
        }
    }
    __syncthreads();
  }

  // epilogue: write binarized bits to LDS byte matrix, then pack 64-bit words
#pragma unroll
  for (int i = 0; i < 4; ++i)
#pragma unroll
    for (int j = 0; j < 8; ++j)
      bits[i * 32 + ty][j * 16 + tx] = (acc[i][j] >= 0.0f) ? 1u : 0u;
  __syncthreads();

  if (t < 256) {
    int b = t >> 1, w = t & 1;
    u64 word = 0;
#pragma unroll
    for (int q = 0; q < 8; ++q) {
      u64 v = *reinterpret_cast<const u64*>(&bits[b][w * 64 + q * 8]);
#pragma unroll
      for (int m = 0; m < 8; ++m)
        word |= ((v >> (8 * m)) & 1ull) << (q * 8 + m);
    }
    int rem = O_DIM - (o0 + w * 64);             // valid bits in this word
    if (rem <= 0) word = ~0ull;
    else if (rem < 64) word |= (~0ull << rem);   // pad bits = 1
    int widx = ot * 2 + w;
    if (widx < NWORDS)
      h1b[(size_t)(b0 + b) * NWORDS + widx] = word;
  }
}

// -------- layer 2: binary-binary via XOR+popcount; exact integers, emits packed h2 --------
__global__ __launch_bounds__(256) void l2_kernel(const u64* __restrict__ h1b,
                                                 const u64* __restrict__ w1b,
                                                 u64* __restrict__ h2b) {
  __shared__ u64 hs[64][NWORDS];
  const int bt = blockIdx.x;
  const int t = threadIdx.x;
  for (int i = t; i < 64 * NWORDS; i += 256)
    hs[i / NWORDS][i % NWORDS] = h1b[(size_t)(bt * 64 + i / NWORDS) * NWORDS + i % NWORDS];
  __syncthreads();

  const int w = t >> 6, l = t & 63;
  for (int oc = w; oc < NWORDS; oc += 4) {
    int o = oc * 64 + l;
    bool valid = (o < O_DIM);
    int orow = valid ? o : (O_DIM - 1);
    u64 wb[NWORDS];
#pragma unroll
    for (int j = 0; j < NWORDS; ++j) wb[j] = w1b[(size_t)orow * NWORDS + j];
    for (int b = 0; b < 64; ++b) {
      int p = 0;
#pragma unroll
      for (int j = 0; j < NWORDS; ++j) p += __popcll(hs[b][j] ^ wb[j]);
      int lin = K_DIM - 2 * p;                   // exact, odd => never 0
      bool bit = valid ? (lin >= 0) : true;      // pad bits = 1
      u64 word = __ballot(bit);
      if (l == 0) h2b[(size_t)(bt * 64 + b) * NWORDS + oc] = word;
    }
  }
}

// -------- layer 3: single output neuron; map sign -> {0,1} --------
__global__ void l3_kernel(const u64* __restrict__ h2b, const u64* __restrict__ w2b,
                          float* __restrict__ out) {
  int b = blockIdx.x * blockDim.x + threadIdx.x;
  if (b >= B_TOTAL) return;
  int p = 0;
#pragma unroll
  for (int j = 0; j < NWORDS; ++j) p += __popcll(h2b[(size_t)b * NWORDS + j] ^ w2b[j]);
  out[b] = ((K_DIM - 2 * p) >= 0) ? 1.0f : 0.0f;
}

extern "C" void kernel_launch(void* const* d_in, const int* in_sizes, int n_in,
                              void* d_out, int out_size, void* d_ws, size_t ws_size,
                              hipStream_t stream) {
  const float* x  = (const float*)d_in[0];
  const float* W0 = (const float*)d_in[1];
  const float* W1 = (const float*)d_in[2];
  const float* W2 = (const float*)d_in[3];
  float* out = (float*)d_out;

  char* ws = (char*)d_ws;
  u64* w1b = (u64*)(ws);               // 1025*17*8 = 139400 B
  u64* w2b = (u64*)(ws + 139776);      // 136 B
  u64* h1b = (u64*)(ws + 140288);      // 16384*17*8 = 2228224 B
  u64* h2b = (u64*)(ws + 2368512);     // 2228224 B  (total ~4.6 MB)

  pack_w_kernel<<<(O_DIM * NWORDS + 255) / 256, 256, 0, stream>>>(W1, O_DIM, w1b);
  pack_w_kernel<<<1, 64, 0, stream>>>(W2, 1, w2b);
  l1_kernel<<<dim3(B_TOTAL / BM, (O_DIM + BN - 1) / BN), 512, 0, stream>>>(x, W0, h1b);
  l2_kernel<<<B_TOTAL / 64, 256, 0, stream>>>(h1b, w1b, h2b);
  l3_kernel<<<B_TOTAL / 256, 256, 0, stream>>>(h2b, w2b, out);
}

// Round 3
// 854.105 us; speedup vs baseline: 28.6856x; 1.2579x over previous
//
#include <hip/hip_runtime.h>
#include <cstdint>

typedef unsigned long long u64;
typedef unsigned short ushort_t;
typedef __attribute__((ext_vector_type(8))) short short8;
typedef __attribute__((ext_vector_type(4))) float f32x4;

#define B_TOTAL 16384
#define K_DIM   1025
#define O_DIM   1025
#define NWORDS  17      // ceil(1025/64); pad bits = 1 on both sides so they cancel in XOR
#define KPAD    1088    // 17 * 64
#define NPAD    1152    // 9 * 128

// round-to-nearest-even f32 -> bf16 (finite inputs)
__device__ __forceinline__ ushort_t f2bf_rne(float f) {
  unsigned u = __float_as_uint(f);
  return (ushort_t)((u + 0x7fffu + ((u >> 16) & 1u)) >> 16);
}

// -------- pack binarized weights into bit-rows: bit=1 <=> w >= 0; pad bits = 1 --------
__global__ void pack_w_kernel(const float* __restrict__ w, int O, u64* __restrict__ out) {
  int idx = blockIdx.x * blockDim.x + threadIdx.x;
  int o = idx / NWORDS, wd = idx % NWORDS;
  if (o >= O) return;
  u64 word = 0;
  int kbase = wd * 64;
  for (int j = 0; j < 64; ++j) {
    int k = kbase + j;
    u64 bit = (k < K_DIM) ? (u64)(w[(size_t)o * K_DIM + k] >= 0.0f) : 1ull;
    word |= bit << j;
  }
  out[idx] = word;
}

// -------- sb[o][k] = +/-1 bf16 of sign(W0), zero-padded to [NPAD][KPAD] --------
__global__ void prep_sb_kernel(const float* __restrict__ w0, ushort_t* __restrict__ sb) {
  int idx = blockIdx.x * blockDim.x + threadIdx.x;
  if (idx >= NPAD * KPAD) return;
  int o = idx / KPAD, k = idx % KPAD;
  ushort_t v = 0;
  if (o < O_DIM && k < K_DIM)
    v = (w0[(size_t)o * K_DIM + k] >= 0.0f) ? 0x3F80 : 0xBF80;
  sb[idx] = v;
}

// -------- errb[b] = rigorous |lin_mfma - lin_ref| bound per row --------
__global__ __launch_bounds__(256) void errb_kernel(const float* __restrict__ x,
                                                   float* __restrict__ errb) {
  __shared__ float red[256];
  int b = blockIdx.x, t = threadIdx.x;
  float s = 0.f;
  for (int k = t; k < K_DIM; k += 256) s += fabsf(x[(size_t)b * K_DIM + k]);
  red[t] = s; __syncthreads();
  for (int st = 128; st > 0; st >>= 1) { if (t < st) red[t] += red[t + st]; __syncthreads(); }
  if (t == 0) errb[b] = red[0] * (1.02f / 65536.0f) + 0.125f;  // 2^-16 quant + slack
}

__global__ void zero_cnt_kernel(unsigned* c) { if (threadIdx.x == 0 && blockIdx.x == 0) *c = 0; }

// -------- layer 1 MFMA: lin = x @ sign(W0)^T via hi/lo bf16 split --------
// 128x128 tile, BK=64, 4 waves (2x2 of 64x64). LDS XOR-swizzled (16B granule).
__global__ __launch_bounds__(256) void l1_mfma_kernel(
    const float* __restrict__ x, const ushort_t* __restrict__ sb,
    const float* __restrict__ errb, u64* __restrict__ h1b,
    unsigned* __restrict__ cnt, unsigned* __restrict__ list, unsigned cap) {
  __shared__ char smem[49152];
  ushort_t* xhi = (ushort_t*)smem;              // [128][64]
  ushort_t* xlo = (ushort_t*)(smem + 16384);    // [128][64]
  ushort_t* ssb = (ushort_t*)(smem + 32768);    // [128][64]
  unsigned char* bits = (unsigned char*)smem;   // union after K-loop: [128][128]
  int* scan = (int*)(smem + 32768);             // union after K-loop

  const int bt = blockIdx.x, ot = blockIdx.y;
  const int b0 = bt * 128, o0 = ot * 128;
  const int t = threadIdx.x;
  const int wave = t >> 6, lane = t & 63;
  const int wm = wave >> 1, wn = wave & 1;
  const int lr = lane & 15, lg = lane >> 4;
  const int r = t >> 1, half = t & 1, c0 = half * 32;
  const int r7 = r & 7;

  f32x4 acc[4][4];
#pragma unroll
  for (int mi = 0; mi < 4; ++mi)
#pragma unroll
    for (int ni = 0; ni < 4; ++ni)
#pragma unroll
      for (int c = 0; c < 4; ++c) acc[mi][ni][c] = 0.0f;

  const float* xrow = x + (size_t)(b0 + r) * K_DIM;
  const ushort_t* sbrow = sb + (size_t)(o0 + r) * KPAD;

  for (int kt = 0; kt < KPAD; kt += 64) {
    // ---- stage A: x -> hi/lo bf16 (scalar loads; x rows are only 4B-aligned) ----
#pragma unroll
    for (int c = 0; c < 4; ++c) {
      int kbase = kt + c0 + c * 8;
      short8 hi, lo;
#pragma unroll
      for (int j = 0; j < 8; ++j) {
        int k = kbase + j;
        float v = (k < K_DIM) ? xrow[k] : 0.0f;
        ushort_t h = f2bf_rne(v);
        float hf = __uint_as_float(((unsigned)h) << 16);
        ushort_t l = f2bf_rne(v - hf);
        hi[j] = (short)h; lo[j] = (short)l;
      }
      int c8h = (half * 4 + c) ^ r7;
      *(short8*)&xhi[r * 64 + c8h * 8] = hi;
      *(short8*)&xlo[r * 64 + c8h * 8] = lo;
    }
    // ---- stage B: sb bf16 copy (16B vector loads, aligned by construction) ----
#pragma unroll
    for (int q = 0; q < 4; ++q) {
      short8 bv = *(const short8*)&sbrow[kt + c0 + q * 8];
      int c8h = (half * 4 + q) ^ r7;
      *(short8*)&ssb[r * 64 + c8h * 8] = bv;
    }
    __syncthreads();

#pragma unroll
    for (int ks = 0; ks < 2; ++ks) {
      short8 af[4], al[4], bf[4];
      const int cbase = ks * 4 + lg;
#pragma unroll
      for (int mi = 0; mi < 4; ++mi) {
        int row = wm * 64 + mi * 16 + lr;
        int c8h = cbase ^ (row & 7);
        af[mi] = *(const short8*)&xhi[row * 64 + c8h * 8];
        al[mi] = *(const short8*)&xlo[row * 64 + c8h * 8];
      }
#pragma unroll
      for (int ni = 0; ni < 4; ++ni) {
        int row = wn * 64 + ni * 16 + lr;
        int c8h = cbase ^ (row & 7);
        bf[ni] = *(const short8*)&ssb[row * 64 + c8h * 8];
      }
#pragma unroll
      for (int mi = 0; mi < 4; ++mi)
#pragma unroll
        for (int ni = 0; ni < 4; ++ni) {
          acc[mi][ni] = __builtin_amdgcn_mfma_f32_16x16x32_bf16(af[mi], bf[ni], acc[mi][ni], 0, 0, 0);
          acc[mi][ni] = __builtin_amdgcn_mfma_f32_16x16x32_bf16(al[mi], bf[ni], acc[mi][ni], 0, 0, 0);
        }
    }
    __syncthreads();
  }

  // ---- epilogue: bits + borderline flags ----
  u64 fw = 0;
#pragma unroll
  for (int mi = 0; mi < 4; ++mi)
#pragma unroll
    for (int ni = 0; ni < 4; ++ni)
#pragma unroll
      for (int rg = 0; rg < 4; ++rg) {
        int lb = wm * 64 + mi * 16 + lg * 4 + rg;   // C/D: row = (lane>>4)*4 + reg  [m89]
        int lo_ = wn * 64 + ni * 16 + lr;           // C/D: col = lane & 15
        float lin = acc[mi][ni][rg];
        bits[lb * 128 + lo_] = (lin >= 0.0f) ? 1u : 0u;
        bool fl = ((o0 + lo_) < O_DIM) && (fabsf(lin) <= errb[b0 + lb]);
        fw |= ((u64)fl) << (mi * 16 + ni * 4 + rg);
      }

  scan[t] = __popcll(fw);
  __syncthreads();
  if (t == 0) {
    int run = 0;
    for (int i = 0; i < 256; ++i) { int c = scan[i]; scan[256 + i] = run; run += c; }
    scan[512] = (run > 0) ? (int)atomicAdd(cnt, (unsigned)run) : 0;
  }
  __syncthreads();

  {
    int off = scan[512] + scan[256 + t];
    u64 f = fw;
    while (f) {
      int e = __ffsll((long long)f) - 1;
      f &= f - 1;
      int mi = e >> 4, ni = (e >> 2) & 3, rg = e & 3;
      int b = b0 + wm * 64 + mi * 16 + lg * 4 + rg;
      int o = o0 + wn * 64 + ni * 16 + lr;
      unsigned abit = (acc[mi][ni][rg] >= 0.0f) ? 1u : 0u;
      if ((unsigned)off < cap)
        list[off] = ((unsigned)b << 12) | ((unsigned)o << 1) | abit;
      ++off;
    }
  }

  // pack bits -> h1b words (pad bits = 1)
  if (t < 256) {
    int b = t >> 1, w = t & 1;
    u64 word = 0;
#pragma unroll
    for (int q = 0; q < 8; ++q) {
      u64 v = *(const u64*)&bits[b * 128 + w * 64 + q * 8];
#pragma unroll
      for (int m = 0; m < 8; ++m)
        word |= ((v >> (8 * m)) & 1ull) << (q * 8 + m);
    }
    int rem = O_DIM - (o0 + w * 64);
    if (rem <= 0) word = ~0ull;
    else if (rem < 64) word |= (~0ull << rem);
    int widx = ot * 2 + w;
    if (widx < NWORDS)
      h1b[(size_t)(b0 + b) * NWORDS + widx] = word;
  }
}

// -------- fixup: exact sequential recompute of flagged elements (bitwise = reference) --------
__global__ void fixup_kernel(const float* __restrict__ x, const u64* __restrict__ w0b,
                             const unsigned* __restrict__ cnt, const unsigned* __restrict__ list,
                             unsigned cap, u64* __restrict__ h1b) {
  unsigned n = *cnt; if (n > cap) n = cap;
  for (unsigned i = blockIdx.x * blockDim.x + threadIdx.x; i < n;
       i += gridDim.x * blockDim.x) {
    unsigned en = list[i];
    int b = (int)(en >> 12), o = (int)((en >> 1) & 0x7ffu);
    unsigned abit = en & 1u;
    const float* xr = x + (size_t)b * K_DIM;
    const u64* wr = w0b + (size_t)o * NWORDS;
    float acc = 0.0f;
    for (int j = 0; j < 16; ++j) {      // k strictly ascending, single accumulator
      u64 wd = wr[j];
#pragma unroll
      for (int m = 0; m < 64; ++m) {
        float v = xr[j * 64 + m];
        unsigned neg = ((unsigned)(wd >> m) & 1u) ^ 1u;
        acc += __uint_as_float(__float_as_uint(v) ^ (neg << 31));
      }
    }
    {
      u64 wd = wr[16];
      float v = xr[1024];
      unsigned neg = ((unsigned)wd & 1u) ^ 1u;
      acc += __uint_as_float(__float_as_uint(v) ^ (neg << 31));
    }
    unsigned nb = (acc >= 0.0f) ? 1u : 0u;
    if (nb != abit)
      atomicXor(&h1b[(size_t)b * NWORDS + (o >> 6)], 1ull << (o & 63));
  }
}

// -------- layers 2+3 fused: XOR+popcount (exact), final sign -> {0,1} --------
__global__ __launch_bounds__(256) void l2l3_kernel(const u64* __restrict__ h1b,
                                                   const u64* __restrict__ w1b,
                                                   const u64* __restrict__ w2b,
                                                   float* __restrict__ out) {
  __shared__ u64 hs[64][NWORDS];
  __shared__ u64 h2[64][NWORDS];
  const int bt = blockIdx.x;
  const int t = threadIdx.x;
  for (int i = t; i < 64 * NWORDS; i += 256)
    hs[i / NWORDS][i % NWORDS] = h1b[(size_t)(bt * 64 + i / NWORDS) * NWORDS + i % NWORDS];
  __syncthreads();

  const int w = t >> 6, l = t & 63;
  for (int oc = w; oc < NWORDS; oc += 4) {
    int o = oc * 64 + l;
    bool valid = (o < O_DIM);
    int orow = valid ? o : (O_DIM - 1);
    u64 wb[NWORDS];
#pragma unroll
    for (int j = 0; j < NWORDS; ++j) wb[j] = w1b[(size_t)orow * NWORDS + j];
    for (int b = 0; b < 64; ++b) {
      int p = 0;
#pragma unroll
      for (int j = 0; j < NWORDS; ++j) p += __popcll(hs[b][j] ^ wb[j]);
      int lin = K_DIM - 2 * p;                 // exact, odd => never 0
      bool bit = valid ? (lin >= 0) : true;    // pad bits = 1
      u64 word = __ballot(bit);
      if (l == 0) h2[b][oc] = word;
    }
  }
  __syncthreads();
  if (t < 64) {
    int p = 0;
#pragma unroll
    for (int j = 0; j < NWORDS; ++j) p += __popcll(h2[t][j] ^ w2b[j]);
    out[bt * 64 + t] = ((K_DIM - 2 * p) >= 0) ? 1.0f : 0.0f;
  }
}

extern "C" void kernel_launch(void* const* d_in, const int* in_sizes, int n_in,
                              void* d_out, int out_size, void* d_ws, size_t ws_size,
                              hipStream_t stream) {
  const float* x  = (const float*)d_in[0];
  const float* W0 = (const float*)d_in[1];
  const float* W1 = (const float*)d_in[2];
  const float* W2 = (const float*)d_in[3];
  float* out = (float*)d_out;

  char* ws = (char*)d_ws;
  u64*      w0b  = (u64*)(ws);                 // 1025*17*8 = 139400 -> pad 139776
  u64*      w1b  = (u64*)(ws + 139776);        // 139400 -> 279552
  u64*      w2b  = (u64*)(ws + 279552);        // 136 -> 280064
  ushort_t* sb   = (ushort_t*)(ws + 280064);   // 1152*1088*2 = 2506752 -> 2786816
  float*    errb = (float*)(ws + 2786816);     // 65536 -> 2852352
  u64*      h1b  = (u64*)(ws + 2852352);       // 2228224 -> 5080576
  unsigned* cnt  = (unsigned*)(ws + 5080576);  // 256 -> 5080832
  unsigned* list = (unsigned*)(ws + 5080832);
  unsigned  cap  = (ws_size > 5080832 + 4) ? (unsigned)((ws_size - 5080832) / 4) : 0;

  pack_w_kernel<<<(O_DIM * NWORDS + 255) / 256, 256, 0, stream>>>(W0, O_DIM, w0b);
  pack_w_kernel<<<(O_DIM * NWORDS + 255) / 256, 256, 0, stream>>>(W1, O_DIM, w1b);
  pack_w_kernel<<<1, 64, 0, stream>>>(W2, 1, w2b);
  prep_sb_kernel<<<(NPAD * KPAD + 255) / 256, 256, 0, stream>>>(W0, sb);
  errb_kernel<<<B_TOTAL, 256, 0, stream>>>(x, errb);
  zero_cnt_kernel<<<1, 64, 0, stream>>>(cnt);
  l1_mfma_kernel<<<dim3(B_TOTAL / 128, NPAD / 128), 256, 0, stream>>>(x, sb, errb, h1b, cnt, list, cap);
  fixup_kernel<<<1024, 256, 0, stream>>>(x, w0b, cnt, list, cap, h1b);
  l2l3_kernel<<<B_TOTAL / 64, 256, 0, stream>>>(h1b, w1b, w2b, out);
}

// Round 4
// 749.132 us; speedup vs baseline: 32.7052x; 1.1401x over previous
//
#include <hip/hip_runtime.h>
#include <cstdint>

typedef unsigned long long u64;
typedef unsigned short ushort_t;
typedef __attribute__((ext_vector_type(8))) short short8;
typedef __attribute__((ext_vector_type(4))) float f32x4;

#define B_TOTAL 16384
#define K_DIM   1025
#define O_DIM   1025
#define NWORDS  17      // ceil(1025/64); pad bits = 1 on both sides so they cancel in XOR
#define KPAD    1088    // 17 * 64
#define NPAD    1152    // 9 * 128

// round-to-nearest-even f32 -> bf16 (finite inputs)
__device__ __forceinline__ ushort_t f2bf_rne(float f) {
  unsigned u = __float_as_uint(f);
  return (ushort_t)((u + 0x7fffu + ((u >> 16) & 1u)) >> 16);
}

// async global->LDS, 16B per lane; LDS dest = wave-uniform base + lane*16
__device__ __forceinline__ void gload16(const ushort_t* g, char* l) {
  __builtin_amdgcn_global_load_lds(
      (const __attribute__((address_space(1))) void*)g,
      (__attribute__((address_space(3))) void*)l, 16, 0, 0);
}

// -------- prep_x: x -> bf16 hi/lo (padded [B][1088]) + errb row bound; one block per row --------
__global__ __launch_bounds__(256) void prep_x_kernel(const float* __restrict__ x,
                                                     ushort_t* __restrict__ xh,
                                                     ushort_t* __restrict__ xl,
                                                     float* __restrict__ errb) {
  __shared__ float red[256];
  const int b = blockIdx.x, t = threadIdx.x;
  float s = 0.0f;
  if (t < 136) {
    const float* xr = x + (size_t)b * K_DIM;
    short8 hi, lo;
#pragma unroll
    for (int j = 0; j < 8; ++j) {
      int k = t * 8 + j;
      float v = (k < K_DIM) ? xr[k] : 0.0f;
      s += fabsf(v);
      ushort_t h = f2bf_rne(v);
      float hf = __uint_as_float((unsigned)h << 16);
      ushort_t l = f2bf_rne(v - hf);
      hi[j] = (short)h; lo[j] = (short)l;
    }
    if (xh) {
      *(short8*)&xh[(size_t)b * KPAD + t * 8] = hi;
      *(short8*)&xl[(size_t)b * KPAD + t * 8] = lo;
    }
  }
  red[t] = s;
  __syncthreads();
  for (int st = 128; st > 0; st >>= 1) { if (t < st) red[t] += red[t + st]; __syncthreads(); }
  if (t == 0) errb[b] = red[0] * (1.02f / 65536.0f) + 0.125f;  // 2^-17 split resid (2x margin) + sum-rounding slack
}

// -------- prep_w0: sign(W0) bf16 rows (padded, zero pad-rows) + W0 bit rows --------
__global__ __launch_bounds__(256) void prep_w0_kernel(const float* __restrict__ w0,
                                                      ushort_t* __restrict__ sb,
                                                      u64* __restrict__ w0b) {
  __shared__ unsigned char by[136];
  const int o = blockIdx.x, t = threadIdx.x;
  if (o >= O_DIM) {                    // pad rows: zero sb (deterministic MFMA input)
    if (t < 136) {
      short8 z = {0, 0, 0, 0, 0, 0, 0, 0};
      *(short8*)&sb[(size_t)o * KPAD + t * 8] = z;
    }
    return;
  }
  if (t < 136) {
    const float* wr = w0 + (size_t)o * K_DIM;
    short8 sv; unsigned m = 0;
#pragma unroll
    for (int j = 0; j < 8; ++j) {
      int k = t * 8 + j;
      bool pos = (k < K_DIM) ? (wr[k] >= 0.0f) : true;
      sv[j] = (short)((k < K_DIM) ? (pos ? 0x3F80 : 0xBF80) : 0);
      m |= (unsigned)pos << j;
    }
    *(short8*)&sb[(size_t)o * KPAD + t * 8] = sv;
    by[t] = (unsigned char)m;
  }
  __syncthreads();
  if (t < NWORDS) {
    u64 word = 0;
#pragma unroll
    for (int q = 0; q < 8; ++q) word |= (u64)by[t * 8 + q] << (8 * q);
    w0b[(size_t)o * NWORDS + t] = word;
  }
}

// -------- pack weight bit-rows (one block per row); optionally zeroes cnt --------
__global__ __launch_bounds__(256) void pack_row_kernel(const float* __restrict__ w,
                                                       u64* __restrict__ out,
                                                       unsigned* cnt) {
  __shared__ unsigned char by[136];
  const int o = blockIdx.x, t = threadIdx.x;
  if (cnt && o == 0 && t == 0) *cnt = 0;
  if (t < 136) {
    const float* wr = w + (size_t)o * K_DIM;
    unsigned m = 0;
#pragma unroll
    for (int j = 0; j < 8; ++j) {
      int k = t * 8 + j;
      bool pos = (k < K_DIM) ? (wr[k] >= 0.0f) : true;
      m |= (unsigned)pos << j;
    }
    by[t] = (unsigned char)m;
  }
  __syncthreads();
  if (t < NWORDS) {
    u64 word = 0;
#pragma unroll
    for (int q = 0; q < 8; ++q) word |= (u64)by[t * 8 + q] << (8 * q);
    out[(size_t)o * NWORDS + t] = word;
  }
}

// -------- layer 1 GEMM (fast path): prematerialized bf16 hi/lo, global_load_lds staging --------
// 128x128 tile, BK=32, 4 waves (2x2 of 64x64), 32 MFMA per K-step (hi+lo chains share B frag).
__global__ __launch_bounds__(256) void l1_gemm_kernel(
    const ushort_t* __restrict__ xh, const ushort_t* __restrict__ xl,
    const ushort_t* __restrict__ sb, const float* __restrict__ errb,
    u64* __restrict__ h1b, unsigned* __restrict__ cnt,
    unsigned* __restrict__ list, unsigned cap) {
  __shared__ char smem[24576 + 2176];
  ushort_t* ldsAh = (ushort_t*)smem;             // [128][32]
  ushort_t* ldsAl = (ushort_t*)(smem + 8192);    // [128][32]
  ushort_t* ldsB  = (ushort_t*)(smem + 16384);   // [128][32]
  unsigned char* bits = (unsigned char*)smem;    // union post-loop: [128][128]
  int* scan = (int*)(smem + 24576);

  const int ot = blockIdx.x, bt = blockIdx.y;
  const int b0 = bt * 128, o0 = ot * 128;
  const int t = threadIdx.x;
  const int wave = t >> 6, lane = t & 63;
  const int wm = wave >> 1, wn = wave & 1;
  const int lr = lane & 15, lg = lane >> 4;

  // staging slots: slot = (wave*2+s)*64 + lane; LDS offset slot*16; row=slot>>2, granule=slot&3
  const int slot0 = wave * 128 + lane;
  const int slot1 = slot0 + 64;
  const int ar0 = slot0 >> 2, ag0 = slot0 & 3;
  const int ar1 = slot1 >> 2, ag1 = slot1 & 3;

  const ushort_t* gAh0 = xh + (size_t)(b0 + ar0) * KPAD + ag0 * 8;
  const ushort_t* gAh1 = xh + (size_t)(b0 + ar1) * KPAD + ag1 * 8;
  const ushort_t* gAl0 = xl + (size_t)(b0 + ar0) * KPAD + ag0 * 8;
  const ushort_t* gAl1 = xl + (size_t)(b0 + ar1) * KPAD + ag1 * 8;
  const ushort_t* gB0  = sb + (size_t)(o0 + ar0) * KPAD + ag0 * 8;
  const ushort_t* gB1  = sb + (size_t)(o0 + ar1) * KPAD + ag1 * 8;

  char* dA0 = smem + wave * 2048;
  char* dA1 = smem + wave * 2048 + 1024;

  f32x4 acc[4][4];
#pragma unroll
  for (int mi = 0; mi < 4; ++mi)
#pragma unroll
    for (int ni = 0; ni < 4; ++ni)
#pragma unroll
      for (int c = 0; c < 4; ++c) acc[mi][ni][c] = 0.0f;

  for (int kt = 0; kt < KPAD; kt += 32) {
    gload16(gAh0 + kt, dA0);
    gload16(gAh1 + kt, dA1);
    gload16(gAl0 + kt, dA0 + 8192);
    gload16(gAl1 + kt, dA1 + 8192);
    gload16(gB0 + kt, dA0 + 16384);
    gload16(gB1 + kt, dA1 + 16384);
    __syncthreads();                        // drains vmcnt(0): tiles resident

    short8 ah[4], al[4], bf[4];
#pragma unroll
    for (int mi = 0; mi < 4; ++mi) {
      int row = wm * 64 + mi * 16 + lr;
      ah[mi] = *(const short8*)&ldsAh[row * 32 + lg * 8];
      al[mi] = *(const short8*)&ldsAl[row * 32 + lg * 8];
    }
#pragma unroll
    for (int ni = 0; ni < 4; ++ni) {
      int row = wn * 64 + ni * 16 + lr;
      bf[ni] = *(const short8*)&ldsB[row * 32 + lg * 8];
    }
#pragma unroll
    for (int mi = 0; mi < 4; ++mi)
#pragma unroll
      for (int ni = 0; ni < 4; ++ni) {
        acc[mi][ni] = __builtin_amdgcn_mfma_f32_16x16x32_bf16(ah[mi], bf[ni], acc[mi][ni], 0, 0, 0);
        acc[mi][ni] = __builtin_amdgcn_mfma_f32_16x16x32_bf16(al[mi], bf[ni], acc[mi][ni], 0, 0, 0);
      }
    __syncthreads();                        // tiles free for next stage
  }

  // ---- epilogue: bits + borderline flags (r3-proven) ----
  u64 fw = 0;
#pragma unroll
  for (int mi = 0; mi < 4; ++mi)
#pragma unroll
    for (int ni = 0; ni < 4; ++ni)
#pragma unroll
      for (int rg = 0; rg < 4; ++rg) {
        int lb = wm * 64 + mi * 16 + lg * 4 + rg;   // C/D: row = (lane>>4)*4 + reg
        int lo_ = wn * 64 + ni * 16 + lr;           // C/D: col = lane & 15
        float lin = acc[mi][ni][rg];
        bits[lb * 128 + lo_] = (lin >= 0.0f) ? 1u : 0u;
        bool fl = ((o0 + lo_) < O_DIM) && (fabsf(lin) <= errb[b0 + lb]);
        fw |= ((u64)fl) << (mi * 16 + ni * 4 + rg);
      }

  scan[t] = __popcll(fw);
  __syncthreads();
  if (t == 0) {
    int run = 0;
    for (int i = 0; i < 256; ++i) { int c = scan[i]; scan[256 + i] = run; run += c; }
    scan[512] = (run > 0) ? (int)atomicAdd(cnt, (unsigned)run) : 0;
  }
  __syncthreads();

  {
    int off = scan[512] + scan[256 + t];
    u64 f = fw;
    while (f) {
      int e = __ffsll((long long)f) - 1;
      f &= f - 1;
      int mi = e >> 4, ni = (e >> 2) & 3, rg = e & 3;
      int b = b0 + wm * 64 + mi * 16 + lg * 4 + rg;
      int o = o0 + wn * 64 + ni * 16 + lr;
      unsigned abit = (acc[mi][ni][rg] >= 0.0f) ? 1u : 0u;
      if ((unsigned)off < cap)
        list[off] = ((unsigned)b << 12) | ((unsigned)o << 1) | abit;
      ++off;
    }
  }

  if (t < 256) {
    int b = t >> 1, w = t & 1;
    u64 word = 0;
#pragma unroll
    for (int q = 0; q < 8; ++q) {
      u64 v = *(const u64*)&bits[b * 128 + w * 64 + q * 8];
#pragma unroll
      for (int m = 0; m < 8; ++m)
        word |= ((v >> (8 * m)) & 1ull) << (q * 8 + m);
    }
    int rem = O_DIM - (o0 + w * 64);
    if (rem <= 0) word = ~0ull;
    else if (rem < 64) word |= (~0ull << rem);
    int widx = ot * 2 + w;
    if (widx < NWORDS)
      h1b[(size_t)(b0 + b) * NWORDS + widx] = word;
  }
}

// -------- layer 1 MFMA (fallback for small ws): r3-proven inline-conversion kernel --------
__global__ __launch_bounds__(256) void l1_mfma_kernel(
    const float* __restrict__ x, const ushort_t* __restrict__ sb,
    const float* __restrict__ errb, u64* __restrict__ h1b,
    unsigned* __restrict__ cnt, unsigned* __restrict__ list, unsigned cap) {
  __shared__ char smem[49152];
  ushort_t* xhi = (ushort_t*)smem;
  ushort_t* xlo = (ushort_t*)(smem + 16384);
  ushort_t* ssb = (ushort_t*)(smem + 32768);
  unsigned char* bits = (unsigned char*)smem;
  int* scan = (int*)(smem + 32768);

  const int bt = blockIdx.x, ot = blockIdx.y;
  const int b0 = bt * 128, o0 = ot * 128;
  const int t = threadIdx.x;
  const int wave = t >> 6, lane = t & 63;
  const int wm = wave >> 1, wn = wave & 1;
  const int lr = lane & 15, lg = lane >> 4;
  const int r = t >> 1, half = t & 1, c0 = half * 32;
  const int r7 = r & 7;

  f32x4 acc[4][4];
#pragma unroll
  for (int mi = 0; mi < 4; ++mi)
#pragma unroll
    for (int ni = 0; ni < 4; ++ni)
#pragma unroll
      for (int c = 0; c < 4; ++c) acc[mi][ni][c] = 0.0f;

  const float* xrow = x + (size_t)(b0 + r) * K_DIM;
  const ushort_t* sbrow = sb + (size_t)(o0 + r) * KPAD;

  for (int kt = 0; kt < KPAD; kt += 64) {
#pragma unroll
    for (int c = 0; c < 4; ++c) {
      int kbase = kt + c0 + c * 8;
      short8 hi, lo;
#pragma unroll
      for (int j = 0; j < 8; ++j) {
        int k = kbase + j;
        float v = (k < K_DIM) ? xrow[k] : 0.0f;
        ushort_t h = f2bf_rne(v);
        float hf = __uint_as_float(((unsigned)h) << 16);
        ushort_t l = f2bf_rne(v - hf);
        hi[j] = (short)h; lo[j] = (short)l;
      }
      int c8h = (half * 4 + c) ^ r7;
      *(short8*)&xhi[r * 64 + c8h * 8] = hi;
      *(short8*)&xlo[r * 64 + c8h * 8] = lo;
    }
#pragma unroll
    for (int q = 0; q < 4; ++q) {
      short8 bv = *(const short8*)&sbrow[kt + c0 + q * 8];
      int c8h = (half * 4 + q) ^ r7;
      *(short8*)&ssb[r * 64 + c8h * 8] = bv;
    }
    __syncthreads();

#pragma unroll
    for (int ks = 0; ks < 2; ++ks) {
      short8 af[4], al[4], bf[4];
      const int cbase = ks * 4 + lg;
#pragma unroll
      for (int mi = 0; mi < 4; ++mi) {
        int row = wm * 64 + mi * 16 + lr;
        int c8h = cbase ^ (row & 7);
        af[mi] = *(const short8*)&xhi[row * 64 + c8h * 8];
        al[mi] = *(const short8*)&xlo[row * 64 + c8h * 8];
      }
#pragma unroll
      for (int ni = 0; ni < 4; ++ni) {
        int row = wn * 64 + ni * 16 + lr;
        int c8h = cbase ^ (row & 7);
        bf[ni] = *(const short8*)&ssb[row * 64 + c8h * 8];
      }
#pragma unroll
      for (int mi = 0; mi < 4; ++mi)
#pragma unroll
        for (int ni = 0; ni < 4; ++ni) {
          acc[mi][ni] = __builtin_amdgcn_mfma_f32_16x16x32_bf16(af[mi], bf[ni], acc[mi][ni], 0, 0, 0);
          acc[mi][ni] = __builtin_amdgcn_mfma_f32_16x16x32_bf16(al[mi], bf[ni], acc[mi][ni], 0, 0, 0);
        }
    }
    __syncthreads();
  }

  u64 fw = 0;
#pragma unroll
  for (int mi = 0; mi < 4; ++mi)
#pragma unroll
    for (int ni = 0; ni < 4; ++ni)
#pragma unroll
      for (int rg = 0; rg < 4; ++rg) {
        int lb = wm * 64 + mi * 16 + lg * 4 + rg;
        int lo_ = wn * 64 + ni * 16 + lr;
        float lin = acc[mi][ni][rg];
        bits[lb * 128 + lo_] = (lin >= 0.0f) ? 1u : 0u;
        bool fl = ((o0 + lo_) < O_DIM) && (fabsf(lin) <= errb[b0 + lb]);
        fw |= ((u64)fl) << (mi * 16 + ni * 4 + rg);
      }

  scan[t] = __popcll(fw);
  __syncthreads();
  if (t == 0) {
    int run = 0;
    for (int i = 0; i < 256; ++i) { int c = scan[i]; scan[256 + i] = run; run += c; }
    scan[512] = (run > 0) ? (int)atomicAdd(cnt, (unsigned)run) : 0;
  }
  __syncthreads();

  {
    int off = scan[512] + scan[256 + t];
    u64 f = fw;
    while (f) {
      int e = __ffsll((long long)f) - 1;
      f &= f - 1;
      int mi = e >> 4, ni = (e >> 2) & 3, rg = e & 3;
      int b = b0 + wm * 64 + mi * 16 + lg * 4 + rg;
      int o = o0 + wn * 64 + ni * 16 + lr;
      unsigned abit = (acc[mi][ni][rg] >= 0.0f) ? 1u : 0u;
      if ((unsigned)off < cap)
        list[off] = ((unsigned)b << 12) | ((unsigned)o << 1) | abit;
      ++off;
    }
  }

  if (t < 256) {
    int b = t >> 1, w = t & 1;
    u64 word = 0;
#pragma unroll
    for (int q = 0; q < 8; ++q) {
      u64 v = *(const u64*)&bits[b * 128 + w * 64 + q * 8];
#pragma unroll
      for (int m = 0; m < 8; ++m)
        word |= ((v >> (8 * m)) & 1ull) << (q * 8 + m);
    }
    int rem = O_DIM - (o0 + w * 64);
    if (rem <= 0) word = ~0ull;
    else if (rem < 64) word |= (~0ull << rem);
    int widx = ot * 2 + w;
    if (widx < NWORDS)
      h1b[(size_t)(b0 + b) * NWORDS + widx] = word;
  }
}

// -------- fixup: exact sequential recompute of flagged elements (bitwise = reference) --------
__global__ void fixup_kernel(const float* __restrict__ x, const u64* __restrict__ w0b,
                             const unsigned* __restrict__ cnt, const unsigned* __restrict__ list,
                             unsigned cap, u64* __restrict__ h1b) {
  unsigned n = *cnt; if (n > cap) n = cap;
  for (unsigned i = blockIdx.x * blockDim.x + threadIdx.x; i < n;
       i += gridDim.x * blockDim.x) {
    unsigned en = list[i];
    int b = (int)(en >> 12), o = (int)((en >> 1) & 0x7ffu);
    unsigned abit = en & 1u;
    const float* xr = x + (size_t)b * K_DIM;
    const u64* wr = w0b + (size_t)o * NWORDS;
    float acc = 0.0f;
    for (int j = 0; j < 16; ++j) {      // k strictly ascending, single accumulator
      u64 wd = wr[j];
#pragma unroll
      for (int m = 0; m < 64; ++m) {
        float v = xr[j * 64 + m];
        unsigned neg = ((unsigned)(wd >> m) & 1u) ^ 1u;
        acc += __uint_as_float(__float_as_uint(v) ^ (neg << 31));
      }
    }
    {
      u64 wd = wr[16];
      float v = xr[1024];
      unsigned neg = ((unsigned)wd & 1u) ^ 1u;
      acc += __uint_as_float(__float_as_uint(v) ^ (neg << 31));
    }
    unsigned nb = (acc >= 0.0f) ? 1u : 0u;
    if (nb != abit)
      atomicXor(&h1b[(size_t)b * NWORDS + (o >> 6)], 1ull << (o & 63));
  }
}

// -------- layers 2+3 fused: XOR+popcount (exact), final sign -> {0,1} --------
__global__ __launch_bounds__(256) void l2l3_kernel(const u64* __restrict__ h1b,
                                                   const u64* __restrict__ w1b,
                                                   const u64* __restrict__ w2b,
                                                   float* __restrict__ out) {
  __shared__ u64 hs[64][NWORDS];
  __shared__ u64 h2[64][NWORDS];
  const int bt = blockIdx.x;
  const int t = threadIdx.x;
  for (int i = t; i < 64 * NWORDS; i += 256)
    hs[i / NWORDS][i % NWORDS] = h1b[(size_t)(bt * 64 + i / NWORDS) * NWORDS + i % NWORDS];
  __syncthreads();

  const int w = t >> 6, l = t & 63;
  for (int oc = w; oc < NWORDS; oc += 4) {
    int o = oc * 64 + l;
    bool valid = (o < O_DIM);
    int orow = valid ? o : (O_DIM - 1);
    u64 wb[NWORDS];
#pragma unroll
    for (int j = 0; j < NWORDS; ++j) wb[j] = w1b[(size_t)orow * NWORDS + j];
    for (int b = 0; b < 64; ++b) {
      int p = 0;
#pragma unroll
      for (int j = 0; j < NWORDS; ++j) p += __popcll(hs[b][j] ^ wb[j]);
      int lin = K_DIM - 2 * p;
      bool bit = valid ? (lin >= 0) : true;
      u64 word = __ballot(bit);
      if (l == 0) h2[b][oc] = word;
    }
  }
  __syncthreads();
  if (t < 64) {
    int p = 0;
#pragma unroll
    for (int j = 0; j < NWORDS; ++j) p += __popcll(h2[t][j] ^ w2b[j]);
    out[bt * 64 + t] = ((K_DIM - 2 * p) >= 0) ? 1.0f : 0.0f;
  }
}

extern "C" void kernel_launch(void* const* d_in, const int* in_sizes, int n_in,
                              void* d_out, int out_size, void* d_ws, size_t ws_size,
                              hipStream_t stream) {
  const float* x  = (const float*)d_in[0];
  const float* W0 = (const float*)d_in[1];
  const float* W1 = (const float*)d_in[2];
  const float* W2 = (const float*)d_in[3];
  float* out = (float*)d_out;

  char* ws = (char*)d_ws;
  // shared low region (both paths)
  u64*      w0b  = (u64*)(ws);                   //      0 .. 139776
  u64*      w1b  = (u64*)(ws + 139776);          // .. 279552
  u64*      w2b  = (u64*)(ws + 279552);          // .. 279808
  float*    errb = (float*)(ws + 279808);        // .. 345344
  ushort_t* sb   = (ushort_t*)(ws + 345344);     // 1152*1088*2 .. 2852096
  u64*      h1b  = (u64*)(ws + 2852096);         // .. 5080320
  unsigned* cnt  = (unsigned*)(ws + 5080320);    // .. 5080576
  // fast-path extras
  const size_t XH_OFF = 5080576;                 // 16384*1088*2 = 35651584
  const size_t XL_OFF = XH_OFF + 35651584;       // .. 76383744
  const size_t LIST_BIG = XL_OFF + 35651584;
  const size_t LIST_SMALL = 5080576;

  bool big = ws_size >= LIST_BIG + (1u << 20);
  ushort_t* xh = (ushort_t*)(ws + XH_OFF);
  ushort_t* xl = (ushort_t*)(ws + XL_OFF);
  size_t list_off = big ? LIST_BIG : LIST_SMALL;
  unsigned* list = (unsigned*)(ws + list_off);
  unsigned  cap  = (ws_size > list_off + 4) ? (unsigned)((ws_size - list_off) / 4) : 0;

  prep_x_kernel<<<B_TOTAL, 256, 0, stream>>>(x, big ? xh : nullptr, big ? xl : nullptr, errb);
  prep_w0_kernel<<<NPAD, 256, 0, stream>>>(W0, sb, w0b);
  pack_row_kernel<<<O_DIM, 256, 0, stream>>>(W1, w1b, nullptr);
  pack_row_kernel<<<1, 256, 0, stream>>>(W2, w2b, cnt);   // also zeroes cnt
  if (big) {
    l1_gemm_kernel<<<dim3(NPAD / 128, B_TOTAL / 128), 256, 0, stream>>>(
        xh, xl, sb, errb, h1b, cnt, list, cap);
  } else {
    l1_mfma_kernel<<<dim3(B_TOTAL / 128, NPAD / 128), 256, 0, stream>>>(
        x, sb, errb, h1b, cnt, list, cap);
  }
  fixup_kernel<<<1024, 256, 0, stream>>>(x, w0b, cnt, list, cap, h1b);
  l2l3_kernel<<<B_TOTAL / 64, 256, 0, stream>>>(h1b, w1b, w2b, out);
}

// Round 5
// 254.309 us; speedup vs baseline: 96.3412x; 2.9458x over previous
//
#include <hip/hip_runtime.h>
#include <cstdint>

typedef unsigned long long u64;
typedef unsigned short ushort_t;
typedef __attribute__((ext_vector_type(8))) short short8;
typedef __attribute__((ext_vector_type(4))) float f32x4;

#define B_TOTAL 16384
#define K_DIM   1025
#define O_DIM   1025
#define NWORDS  17        // ceil(1025/64)
#define NKT     34        // K tiles of 32 (covers 1088)
#define NFRAG   72        // n-fragments of 16 (covers 1152)
#define A_BYTES 8192      // per (panel,kt): 4 hi frags + 4 lo frags, 1 KB each
#define B_BYTES 73728     // per kt: 72 frags, 1 KB each
#define STEP_BYTES (A_BYTES + B_BYTES)   // 81920; double-buffered = 160 KB LDS

// round-to-nearest-even f32 -> bf16 (finite inputs)
__device__ __forceinline__ ushort_t f2bf_rne(float f) {
  unsigned u = __float_as_uint(f);
  return (ushort_t)((u + 0x7fffu + ((u >> 16) & 1u)) >> 16);
}

// async global->LDS, 16B per lane; LDS dest = wave-uniform base + lane*16
__device__ __forceinline__ void gload16(const ushort_t* g, char* l) {
  __builtin_amdgcn_global_load_lds(
      (const __attribute__((address_space(1))) void*)g,
      (__attribute__((address_space(3))) void*)l, 16, 0, 0);
}

// -------- pack all weight bit-rows (W0|W1|W2) + zero cnt --------
__global__ __launch_bounds__(256) void pack_all_kernel(const float* __restrict__ W0,
                                                       const float* __restrict__ W1,
                                                       const float* __restrict__ W2,
                                                       u64* __restrict__ w0b,
                                                       u64* __restrict__ w1b,
                                                       u64* __restrict__ w2b,
                                                       unsigned* cnt) {
  __shared__ unsigned char by[136];
  const int row = blockIdx.x, t = threadIdx.x;
  if (row == 0 && t == 0) *cnt = 0;
  const float* src; u64* dst; int o;
  if (row < O_DIM)           { src = W0; dst = w0b; o = row; }
  else if (row < 2 * O_DIM)  { src = W1; dst = w1b; o = row - O_DIM; }
  else                       { src = W2; dst = w2b; o = 0; }
  if (t < 136) {
    const float* wr = src + (size_t)o * K_DIM;
    unsigned m = 0;
#pragma unroll
    for (int j = 0; j < 8; ++j) {
      int k = t * 8 + j;
      bool pos = (k < K_DIM) ? (wr[k] >= 0.0f) : true;
      m |= (unsigned)pos << j;
    }
    by[t] = (unsigned char)m;
  }
  __syncthreads();
  if (t < NWORDS) {
    u64 word = 0;
#pragma unroll
    for (int q = 0; q < 8; ++q) word |= (u64)by[t * 8 + q] << (8 * q);
    dst[(size_t)o * NWORDS + t] = word;
  }
}

// -------- prep_sbf: sign(W0) in MFMA-fragment order: [kt][nf][lane][8 shorts] --------
// fragment (kt,nf), lane l holds B[o = nf*16 + (l&15)][k = kt*32 + (l>>4)*8 + j]
__global__ __launch_bounds__(256) void prep_sbf_kernel(const float* __restrict__ w0,
                                                       ushort_t* __restrict__ sbf) {
  const int t = threadIdx.x;
  const int f = blockIdx.x * 4 + (t >> 6);        // 0..2447 = kt*72+nf
  const int lane = t & 63;
  const int kt = f / NFRAG, nf = f % NFRAG;
  const int o = nf * 16 + (lane & 15);
  const int kbase = kt * 32 + (lane >> 4) * 8;
  short8 sv;
#pragma unroll
  for (int j = 0; j < 8; ++j) {
    int k = kbase + j;
    short v = 0;
    if (o < O_DIM && k < K_DIM)
      v = (short)((w0[(size_t)o * K_DIM + k] >= 0.0f) ? 0x3F80 : 0xBF80);
    sv[j] = v;
  }
  *(short8*)&sbf[(size_t)f * 512 + lane * 8] = sv;
}

// -------- prep_xf: x -> hi/lo bf16 in fragment order + errb --------
// layout: [panel][kt][slot 0..7][lane][8], slot 0-3 = hi(mf), 4-7 = lo(mf)
__global__ __launch_bounds__(256) void prep_xf_kernel(const float* __restrict__ x,
                                                      ushort_t* __restrict__ xf,
                                                      float* __restrict__ errb) {
  const int p = blockIdx.x, t = threadIdx.x;
  const int mf = t >> 6, lane = t & 63;
  const int lr = lane & 15, lg = lane >> 4;
  const int brow = p * 64 + mf * 16 + lr;
  const float* xr = x + (size_t)brow * K_DIM;
  float s = 0.0f;
  for (int kt = 0; kt < NKT; ++kt) {
    const int kbase = kt * 32 + lg * 8;
    float v[8];
    if (kbase + 8 <= K_DIM) {
      float4 a = *(const float4*)(xr + kbase);
      float4 b = *(const float4*)(xr + kbase + 4);
      v[0]=a.x; v[1]=a.y; v[2]=a.z; v[3]=a.w; v[4]=b.x; v[5]=b.y; v[6]=b.z; v[7]=b.w;
    } else {
#pragma unroll
      for (int j = 0; j < 8; ++j) v[j] = (kbase + j < K_DIM) ? xr[kbase + j] : 0.0f;
    }
    short8 hi, lo;
#pragma unroll
    for (int j = 0; j < 8; ++j) {
      s += fabsf(v[j]);
      ushort_t h = f2bf_rne(v[j]);
      float hf = __uint_as_float((unsigned)h << 16);
      ushort_t l = f2bf_rne(v[j] - hf);
      hi[j] = (short)h; lo[j] = (short)l;
    }
    size_t base = ((size_t)(p * NKT + kt) * 8 + mf) * 512 + lane * 8;
    *(short8*)&xf[base] = hi;
    *(short8*)&xf[base + 4 * 512] = lo;
  }
  s += __shfl_xor(s, 16, 64);
  s += __shfl_xor(s, 32, 64);
  if (lg == 0) errb[brow] = s * (1.02f / 65536.0f) + 0.125f;
}

// -------- layer 1 GEMM: output-stationary, full N per block --------
// 256 blocks (64 b-rows each), 8 waves, acc = 4 mf x 9 nf frags/wave.
// LDS: 2 x 80 KB buffers, layout identical to global fragment order.
__global__ __launch_bounds__(512, 2) void l1_gemm_kernel(
    const ushort_t* __restrict__ xf, const ushort_t* __restrict__ sbf,
    const float* __restrict__ errb, u64* __restrict__ h1b,
    unsigned* __restrict__ cnt, unsigned* __restrict__ list, unsigned cap) {
  extern __shared__ char smem[];
  const int p = blockIdx.x;
  const int t = threadIdx.x;
  const int wave = t >> 6, lane = t & 63;
  const int lr = lane & 15, lg = lane >> 4;
  const int b0 = p * 64;
  const int obase = wave * 144;                  // wave's n-column base (9 frags)

  const ushort_t* gA = xf + (size_t)p * NKT * (A_BYTES / 2);

  f32x4 acc[4][9];
#pragma unroll
  for (int mf = 0; mf < 4; ++mf)
#pragma unroll
    for (int nfl = 0; nfl < 9; ++nfl)
#pragma unroll
      for (int c = 0; c < 4; ++c) acc[mf][nfl][c] = 0.0f;

#define STAGE(BUFI, KT)                                                        \
  {                                                                            \
    char* dbuf = smem + (BUFI) * STEP_BYTES;                                   \
    _Pragma("unroll")                                                          \
    for (int i = 0; i < 10; ++i) {                                             \
      int s = wave * 10 + i;                                                   \
      const ushort_t* g = (s < 8)                                              \
          ? gA + (KT) * (A_BYTES / 2) + s * 512 + lane * 8                     \
          : sbf + (size_t)(KT) * (B_BYTES / 2) + (s - 8) * 512 + lane * 8;     \
      gload16(g, dbuf + s * 1024);                                             \
    }                                                                          \
  }

  STAGE(0, 0);
  __syncthreads();
  int cur = 0;
  for (int kt = 0; kt < NKT; ++kt) {
    if (kt + 1 < NKT) STAGE(cur ^ 1, kt + 1);
    const ushort_t* A = (const ushort_t*)(smem + cur * STEP_BYTES);
    const ushort_t* Bf = A + A_BYTES / 2;
    short8 ah[4], al[4];
#pragma unroll
    for (int mf = 0; mf < 4; ++mf) {
      ah[mf] = *(const short8*)&A[mf * 512 + lane * 8];
      al[mf] = *(const short8*)&A[(4 + mf) * 512 + lane * 8];
    }
#pragma unroll
    for (int nfl = 0; nfl < 9; ++nfl) {
      short8 bv = *(const short8*)&Bf[(wave * 9 + nfl) * 512 + lane * 8];
#pragma unroll
      for (int mf = 0; mf < 4; ++mf) {
        acc[mf][nfl] = __builtin_amdgcn_mfma_f32_16x16x32_bf16(ah[mf], bv, acc[mf][nfl], 0, 0, 0);
        acc[mf][nfl] = __builtin_amdgcn_mfma_f32_16x16x32_bf16(al[mf], bv, acc[mf][nfl], 0, 0, 0);
      }
    }
    __syncthreads();     // drains vmcnt(0): next tile resident; cur free for reuse
    cur ^= 1;
  }
#undef STAGE

  // ---- epilogue: bits + borderline flags ----
  unsigned char* bits = (unsigned char*)smem;    // [64][1152]
  int* scan = (int*)(smem + 73728);              // 17 ints

  float eb[4][4];
#pragma unroll
  for (int mf = 0; mf < 4; ++mf)
#pragma unroll
    for (int rg = 0; rg < 4; ++rg) eb[mf][rg] = errb[b0 + mf * 16 + lg * 4 + rg];

  int myCnt = 0;
#pragma unroll
  for (int mf = 0; mf < 4; ++mf)
#pragma unroll
    for (int nfl = 0; nfl < 9; ++nfl)
#pragma unroll
      for (int rg = 0; rg < 4; ++rg) {
        int bl = mf * 16 + lg * 4 + rg;          // C/D: row = (lane>>4)*4 + reg
        int o  = obase + nfl * 16 + lr;          // C/D: col = lane & 15
        float lin = acc[mf][nfl][rg];
        bits[bl * 1152 + o] = (lin >= 0.0f) ? 1u : 0u;
        myCnt += (int)((o < O_DIM) && (fabsf(lin) <= eb[mf][rg]));
      }

  // wave-level inclusive prefix of flag counts
  int incl = myCnt;
#pragma unroll
  for (int d = 1; d < 64; d <<= 1) {
    int v = __shfl_up(incl, d, 64);
    if (lane >= d) incl += v;
  }
  if (lane == 63) scan[wave] = incl;
  __syncthreads();
  if (t == 0) {
    int run = 0;
#pragma unroll
    for (int i = 0; i < 8; ++i) { int c = scan[i]; scan[8 + i] = run; run += c; }
    scan[16] = (run > 0) ? (int)atomicAdd(cnt, (unsigned)run) : 0;
  }
  __syncthreads();

  {
    int off = scan[16] + scan[8 + wave] + incl - myCnt;
#pragma unroll
    for (int mf = 0; mf < 4; ++mf)
#pragma unroll
      for (int nfl = 0; nfl < 9; ++nfl)
#pragma unroll
        for (int rg = 0; rg < 4; ++rg) {
          int o = obase + nfl * 16 + lr;
          float lin = acc[mf][nfl][rg];
          if ((o < O_DIM) && (fabsf(lin) <= eb[mf][rg])) {
            int b = b0 + mf * 16 + lg * 4 + rg;
            unsigned abit = (lin >= 0.0f) ? 1u : 0u;
            if ((unsigned)off < cap)
              list[off] = ((unsigned)b << 12) | ((unsigned)o << 1) | abit;
            ++off;
          }
        }
  }

  // pack bits -> h1b (pad bits = 1); 64 rows x 17 words
  for (int task = t; task < 64 * NWORDS; task += 512) {
    int row = task / NWORDS, w = task % NWORDS;
    u64 word = 0;
#pragma unroll
    for (int q = 0; q < 8; ++q) {
      u64 v = *(const u64*)&bits[row * 1152 + w * 64 + q * 8];
#pragma unroll
      for (int m = 0; m < 8; ++m)
        word |= ((v >> (8 * m)) & 1ull) << (q * 8 + m);
    }
    int rem = O_DIM - w * 64;
    if (rem < 64) word |= (~0ull << rem);
    h1b[(size_t)(b0 + row) * NWORDS + w] = word;
  }
}

// -------- fixup: exact sequential recompute of flagged elements (bitwise = reference) --------
__global__ void fixup_kernel(const float* __restrict__ x, const u64* __restrict__ w0b,
                             const unsigned* __restrict__ cnt, const unsigned* __restrict__ list,
                             unsigned cap, u64* __restrict__ h1b) {
  unsigned n = *cnt; if (n > cap) n = cap;
  for (unsigned i = blockIdx.x * blockDim.x + threadIdx.x; i < n;
       i += gridDim.x * blockDim.x) {
    unsigned en = list[i];
    int b = (int)(en >> 12), o = (int)((en >> 1) & 0x7ffu);
    unsigned abit = en & 1u;
    const float* xr = x + (size_t)b * K_DIM;
    const u64* wr = w0b + (size_t)o * NWORDS;
    float acc = 0.0f;
    for (int j = 0; j < 16; ++j) {      // k strictly ascending, single accumulator
      u64 wd = wr[j];
#pragma unroll
      for (int m = 0; m < 64; ++m) {
        float v = xr[j * 64 + m];
        unsigned neg = ((unsigned)(wd >> m) & 1u) ^ 1u;
        acc += __uint_as_float(__float_as_uint(v) ^ (neg << 31));
      }
    }
    {
      u64 wd = wr[16];
      float v = xr[1024];
      unsigned neg = ((unsigned)wd & 1u) ^ 1u;
      acc += __uint_as_float(__float_as_uint(v) ^ (neg << 31));
    }
    unsigned nb = (acc >= 0.0f) ? 1u : 0u;
    if (nb != abit)
      atomicXor(&h1b[(size_t)b * NWORDS + (o >> 6)], 1ull << (o & 63));
  }
}

// -------- layers 2+3 fused: XOR+popcount (exact), final sign -> {0,1} --------
__global__ __launch_bounds__(256) void l2l3_kernel(const u64* __restrict__ h1b,
                                                   const u64* __restrict__ w1b,
                                                   const u64* __restrict__ w2b,
                                                   float* __restrict__ out) {
  __shared__ u64 hs[64][NWORDS];
  __shared__ u64 h2[64][NWORDS];
  const int bt = blockIdx.x;
  const int t = threadIdx.x;
  for (int i = t; i < 64 * NWORDS; i += 256)
    hs[i / NWORDS][i % NWORDS] = h1b[(size_t)(bt * 64 + i / NWORDS) * NWORDS + i % NWORDS];
  __syncthreads();

  const int w = t >> 6, l = t & 63;
  for (int oc = w; oc < NWORDS; oc += 4) {
    int o = oc * 64 + l;
    bool valid = (o < O_DIM);
    int orow = valid ? o : (O_DIM - 1);
    u64 wb[NWORDS];
#pragma unroll
    for (int j = 0; j < NWORDS; ++j) wb[j] = w1b[(size_t)orow * NWORDS + j];
    for (int b = 0; b < 64; ++b) {
      int p = 0;
#pragma unroll
      for (int j = 0; j < NWORDS; ++j) p += __popcll(hs[b][j] ^ wb[j]);
      int lin = K_DIM - 2 * p;                 // exact, odd => never 0
      bool bit = valid ? (lin >= 0) : true;    // pad bits = 1
      u64 word = __ballot(bit);
      if (l == 0) h2[b][oc] = word;
    }
  }
  __syncthreads();
  if (t < 64) {
    int p = 0;
#pragma unroll
    for (int j = 0; j < NWORDS; ++j) p += __popcll(h2[t][j] ^ w2b[j]);
    out[bt * 64 + t] = ((K_DIM - 2 * p) >= 0) ? 1.0f : 0.0f;
  }
}

extern "C" void kernel_launch(void* const* d_in, const int* in_sizes, int n_in,
                              void* d_out, int out_size, void* d_ws, size_t ws_size,
                              hipStream_t stream) {
  const float* x  = (const float*)d_in[0];
  const float* W0 = (const float*)d_in[1];
  const float* W1 = (const float*)d_in[2];
  const float* W2 = (const float*)d_in[3];
  float* out = (float*)d_out;

  char* ws = (char*)d_ws;
  u64*      w0b  = (u64*)(ws);                   //       0 .. 139776
  u64*      w1b  = (u64*)(ws + 139776);          // .. 279552
  u64*      w2b  = (u64*)(ws + 279552);          // .. 279808
  float*    errb = (float*)(ws + 279808);        // .. 345344
  u64*      h1b  = (u64*)(ws + 345344);          // .. 2573568
  unsigned* cnt  = (unsigned*)(ws + 2573568);    // .. 2573824
  ushort_t* sbf  = (ushort_t*)(ws + 2573824);    // 2506752 .. 5080576
  ushort_t* xf   = (ushort_t*)(ws + 5080576);    // 71303168 .. 76383744
  unsigned* list = (unsigned*)(ws + 76383744);
  unsigned  cap  = (ws_size > 76383744 + 4) ? (unsigned)((ws_size - 76383744) / 4) : 0;

  static bool attr_set = false;
  if (!attr_set) {
    hipFuncSetAttribute((const void*)l1_gemm_kernel,
                        hipFuncAttributeMaxDynamicSharedMemorySize, 2 * STEP_BYTES);
    attr_set = true;
  }

  pack_all_kernel<<<2 * O_DIM + 1, 256, 0, stream>>>(W0, W1, W2, w0b, w1b, w2b, cnt);
  prep_sbf_kernel<<<NKT * NFRAG / 4, 256, 0, stream>>>(W0, sbf);
  prep_xf_kernel<<<B_TOTAL / 64, 256, 0, stream>>>(x, xf, errb);
  l1_gemm_kernel<<<B_TOTAL / 64, 512, 2 * STEP_BYTES, stream>>>(
      xf, sbf, errb, h1b, cnt, list, cap);
  fixup_kernel<<<1024, 256, 0, stream>>>(x, w0b, cnt, list, cap, h1b);
  l2l3_kernel<<<B_TOTAL / 64, 256, 0, stream>>>(h1b, w1b, w2b, out);
}